// Round 1
// baseline (229.458 us; speedup 1.0000x reference)
//
#include <hip/hip_runtime.h>
#include <hip/hip_bf16.h>

typedef unsigned short u16;
typedef unsigned int u32;
typedef __attribute__((ext_vector_type(8))) short short8;
typedef __attribute__((ext_vector_type(4))) float f32x4;

// Problem shape (fixed by reference)
#define MM 4096   // B*S = 2*2048
#define NN 4096   // OUT_F
#define KK 4096   // IN_F

__device__ __forceinline__ u16 f2bf(float f) {
  union { float f; u32 u; } v; v.f = f;
  u32 r = v.u + 0x7fffu + ((v.u >> 16) & 1u);   // round-to-nearest-even
  return (u16)(r >> 16);
}

// ---- conversion passes into workspace -------------------------------------
// weights arrive as int32 per harness convention (integer -> const int*)
__global__ __launch_bounds__(256) void cvt_w_k(const int* __restrict__ w,
                                               u16* __restrict__ o) {
  int i = blockIdx.x * 256 + threadIdx.x;      // 8 elements per thread
  const int4* w4 = (const int4*)w;
  int4 a = w4[2 * i];
  int4 b = w4[2 * i + 1];
  short8 r;
  r[0] = (short)f2bf((float)a.x); r[1] = (short)f2bf((float)a.y);
  r[2] = (short)f2bf((float)a.z); r[3] = (short)f2bf((float)a.w);
  r[4] = (short)f2bf((float)b.x); r[5] = (short)f2bf((float)b.y);
  r[6] = (short)f2bf((float)b.z); r[7] = (short)f2bf((float)b.w);
  *(short8*)(o + (size_t)i * 8) = r;
}

__global__ __launch_bounds__(256) void cvt_a_k(const float* __restrict__ x,
                                               u16* __restrict__ o) {
  int i = blockIdx.x * 256 + threadIdx.x;      // 8 elements per thread
  const float4* x4 = (const float4*)x;
  float4 a = x4[2 * i];
  float4 b = x4[2 * i + 1];
  short8 r;
  r[0] = (short)f2bf(a.x); r[1] = (short)f2bf(a.y);
  r[2] = (short)f2bf(a.z); r[3] = (short)f2bf(a.w);
  r[4] = (short)f2bf(b.x); r[5] = (short)f2bf(b.y);
  r[6] = (short)f2bf(b.z); r[7] = (short)f2bf(b.w);
  *(short8*)(o + (size_t)i * 8) = r;
}

// ---- async global->LDS (width 16) -----------------------------------------
__device__ __forceinline__ void gload16(const u16* g, u16* l) {
  __builtin_amdgcn_global_load_lds(
      (const __attribute__((address_space(1))) void*)g,
      (__attribute__((address_space(3))) void*)l, 16, 0, 0);
}

// ---- bf16 GEMM, 128x128 tile, BK=64, 4 waves (m97 structure) ---------------
// A: [M][K] bf16 row-major, W: [N][K] bf16 row-major (B^T input)
// out[m][n] = (sum_k A[m][k]*W[n][k]) * scales[n] + bias[n]
__global__ __launch_bounds__(256) void gemm_k(const u16* __restrict__ A,
                                              const u16* __restrict__ W,
                                              const float* __restrict__ scales,
                                              const float* __restrict__ bias,
                                              float* __restrict__ out) {
  __shared__ u16 As[128 * 64];
  __shared__ u16 Bs[128 * 64];

  // XCD-aware swizzle: nwg = 1024, divisible by 8 -> simple bijective form
  const int nwg = gridDim.x;
  const int cpx = nwg >> 3;
  const int wg = (blockIdx.x & 7) * cpx + (blockIdx.x >> 3);
  const int bm = wg >> 5;        // 32 tiles along N
  const int bn = wg & 31;

  const int tid = threadIdx.x;
  const int lane = tid & 63;
  const int wid = tid >> 6;
  const int wr = wid >> 1;       // 2x2 wave grid; each wave owns 64x64
  const int wc = wid & 1;

  f32x4 acc[4][4] = {};

  const u16* Ag = A + (size_t)bm * 128 * KK;
  const u16* Wg = W + (size_t)bn * 128 * KK;

  for (int k0 = 0; k0 < KK; k0 += 64) {
    // stage A,B tiles: 1024 chunks x 16B each; lane-contiguous LDS dest
#pragma unroll
    for (int c = 0; c < 4; ++c) {
      int chunk = c * 256 + tid;
      int r = chunk >> 3;            // 8 x 16B chunks per 64-elem row
      int kc = (chunk & 7) << 3;
      gload16(Ag + (size_t)r * KK + k0 + kc, &As[chunk * 8]);
      gload16(Wg + (size_t)r * KK + k0 + kc, &Bs[chunk * 8]);
    }
    __syncthreads();

#pragma unroll
    for (int kk = 0; kk < 2; ++kk) {
      const int ko = kk * 32 + (lane >> 4) * 8;
      const int rowa = wr * 64 + (lane & 15);
      const int rowb = wc * 64 + (lane & 15);
      short8 af[4], bf[4];
#pragma unroll
      for (int m = 0; m < 4; ++m)
        af[m] = *(const short8*)(&As[(rowa + m * 16) * 64 + ko]);
#pragma unroll
      for (int n = 0; n < 4; ++n)
        bf[n] = *(const short8*)(&Bs[(rowb + n * 16) * 64 + ko]);
#pragma unroll
      for (int m = 0; m < 4; ++m)
#pragma unroll
        for (int n = 0; n < 4; ++n)
          acc[m][n] =
              __builtin_amdgcn_mfma_f32_16x16x32_bf16(af[m], bf[n], acc[m][n], 0, 0, 0);
    }
    __syncthreads();
  }

  // epilogue: dequant + bias, fp32 store
  // C/D layout (16x16x32): col = lane&15, row = (lane>>4)*4 + reg
  const int colb = bn * 128 + wc * 64 + (lane & 15);
  const int rowb0 = bm * 128 + wr * 64 + ((lane >> 4) << 2);
#pragma unroll
  for (int n = 0; n < 4; ++n) {
    const int col = colb + n * 16;
    const float sc = scales[col];
    const float bi = bias[col];
#pragma unroll
    for (int m = 0; m < 4; ++m) {
      const int row = rowb0 + m * 16;
#pragma unroll
      for (int j = 0; j < 4; ++j)
        out[(size_t)(row + j) * NN + col] = acc[m][n][j] * sc + bi;
    }
  }
}

// ---- fallback (only if ws too small): correct but slow ---------------------
__global__ __launch_bounds__(256) void fb_k(const float* __restrict__ A,
                                            const int* __restrict__ W,
                                            const float* __restrict__ scales,
                                            const float* __restrict__ bias,
                                            float* __restrict__ out) {
  __shared__ float Arow[KK];
  const int m = blockIdx.y;
  const int n0 = blockIdx.x * 256;
  const int tid = threadIdx.x;
  for (int k = tid; k < KK; k += 256) Arow[k] = A[(size_t)m * KK + k];
  __syncthreads();
  const int n = n0 + tid;
  float acc = 0.f;
  const int* wr = W + (size_t)n * KK;
  for (int k = 0; k < KK; ++k) acc += Arow[k] * (float)wr[k];
  out[(size_t)m * NN + n] = acc * scales[n] + bias[n];
}

extern "C" void kernel_launch(void* const* d_in, const int* in_sizes, int n_in,
                              void* d_out, int out_size, void* d_ws, size_t ws_size,
                              hipStream_t stream) {
  const float* input = (const float*)d_in[0];   // [2,2048,4096] fp32
  const int* w8 = (const int*)d_in[1];          // [4096,4096] int (from int8)
  const float* scales = (const float*)d_in[2];  // [4096]
  const float* bias = (const float*)d_in[3];    // [1,4096]
  float* out = (float*)d_out;                   // [2,2048,4096] fp32

  const size_t nelem = (size_t)NN * KK;         // 16,777,216
  const size_t need = 2 * nelem * sizeof(u16);  // 64 MiB

  if (ws_size >= need) {
    u16* Wbf = (u16*)d_ws;
    u16* Abf = Wbf + nelem;
    // 8 elems/thread -> 2,097,152 threads -> 8192 blocks
    cvt_w_k<<<8192, 256, 0, stream>>>(w8, Wbf);
    cvt_a_k<<<8192, 256, 0, stream>>>(input, Abf);
    gemm_k<<<1024, 256, 0, stream>>>(Abf, Wbf, scales, bias, out);
  } else {
    dim3 grid(NN / 256, MM);
    fb_k<<<grid, 256, 0, stream>>>(input, w8, scales, bias, out);
  }
}

// Round 3
// 146.103 us; speedup vs baseline: 1.5705x; 1.5705x over previous
//
#include <hip/hip_runtime.h>
#include <hip/hip_bf16.h>

typedef unsigned short u16;
typedef unsigned int u32;
typedef __attribute__((ext_vector_type(8))) short short8;
typedef __attribute__((ext_vector_type(4))) float f32x4;

#define MM 4096
#define NN 4096
#define KK 4096

#define BAR __builtin_amdgcn_s_barrier()
#define FENCE asm volatile("" ::: "memory")
#define WAITVM(n) asm volatile("s_waitcnt vmcnt(" #n ")" ::: "memory")

// LDS layout: Ab0 @0, Bb0 @16384, Ab1 @32768, Bb1 @49152 (u16 elements)
#define ABUF(sh, b) ((sh) + (b) * 32768)
#define BBUF(sh, b) ((sh) + 16384 + (b) * 32768)

__device__ __forceinline__ u16 f2bf(float f) {
  union { float f; u32 u; } v; v.f = f;
  u32 r = v.u + 0x7fffu + ((v.u >> 16) & 1u);
  return (u16)(r >> 16);
}

// ---- conversion passes ----------------------------------------------------
__global__ __launch_bounds__(256) void cvt_w_k(const int* __restrict__ w,
                                               u16* __restrict__ o) {
  int i = blockIdx.x * 256 + threadIdx.x;
  const int4* w4 = (const int4*)w;
  int4 a = w4[2 * i];
  int4 b = w4[2 * i + 1];
  short8 r;
  r[0] = (short)f2bf((float)a.x); r[1] = (short)f2bf((float)a.y);
  r[2] = (short)f2bf((float)a.z); r[3] = (short)f2bf((float)a.w);
  r[4] = (short)f2bf((float)b.x); r[5] = (short)f2bf((float)b.y);
  r[6] = (short)f2bf((float)b.z); r[7] = (short)f2bf((float)b.w);
  *(short8*)(o + (size_t)i * 8) = r;
}

__global__ __launch_bounds__(256) void cvt_a_k(const float* __restrict__ x,
                                               u16* __restrict__ o) {
  int i = blockIdx.x * 256 + threadIdx.x;
  const float4* x4 = (const float4*)x;
  float4 a = x4[2 * i];
  float4 b = x4[2 * i + 1];
  short8 r;
  r[0] = (short)f2bf(a.x); r[1] = (short)f2bf(a.y);
  r[2] = (short)f2bf(a.z); r[3] = (short)f2bf(a.w);
  r[4] = (short)f2bf(b.x); r[5] = (short)f2bf(b.y);
  r[6] = (short)f2bf(b.z); r[7] = (short)f2bf(b.w);
  *(short8*)(o + (size_t)i * 8) = r;
}

// ---- async global->LDS, width 16 ------------------------------------------
__device__ __forceinline__ void gload16(const u16* g, u16* l) {
  __builtin_amdgcn_global_load_lds(
      (const __attribute__((address_space(1))) void*)g,
      (__attribute__((address_space(3))) void*)l, 16, 0, 0);
}

// Stage one half-tile (128 rows x 64 cols bf16 = 16 KB) into LDS.
// LDS dest is LINEAR (wave-uniform base + lane*16). The T2 swizzle is applied
// by permuting the GLOBAL source 16B-chunk: src chunk = (dest chunk) ^ (row&7).
__device__ __forceinline__ void stage_half(const u16* __restrict__ gRowBase,
                                           int k0, u16* ldsHalf, int tid) {
#pragma unroll
  for (int i = 0; i < 2; ++i) {
    int p = i * 512 + tid;                 // dest 16B-chunk, 0..1023
    int row = p >> 3;                      // 8 chunks per 64-elem row
    int c = (p & 7) ^ (row & 7);           // inverse (== forward) swizzle
    gload16(gRowBase + (size_t)row * KK + k0 + c * 8, ldsHalf + p * 8);
  }
}

// Swizzled ds_read of one 16B MFMA fragment: logical (row r, chunk q).
__device__ __forceinline__ short8 ldsfrag(const u16* base, int r, int q) {
  return *(const short8*)(base + r * 64 + ((q ^ (r & 7)) << 3));
}

// ---- 256x256-tile 8-phase bf16 GEMM, fused dequant epilogue ----------------
// A:[M][K] bf16, W:[N][K] bf16 (B^T), out[m][n] = dot*scales[n]+bias[n]
template <int MODE>  // 0 = steady (t<=61), 1 = t==62, 2 = t==63
__device__ __forceinline__ void do_tile(
    int t, f32x4 (&acc)[8][4], const u16* Ag, const u16* Wg, u16* sh,
    int tid, int lr, int hi, int wr, int wc) {
  const int b = t & 1;
  const u16* Acur = ABUF(sh, b);
  const u16* Bcur = BBUF(sh, b);
  short8 bfr[4][2], afr[4][2];

  // ---- P1: read all B frags + A(mh0); stage (t+1) A1 -> buf b^1
#pragma unroll
  for (int n = 0; n < 4; ++n)
#pragma unroll
    for (int ks = 0; ks < 2; ++ks)
      bfr[n][ks] = ldsfrag(Bcur, wc * 64 + n * 16 + lr, ks * 4 + hi);
#pragma unroll
  for (int m = 0; m < 4; ++m)
#pragma unroll
    for (int ks = 0; ks < 2; ++ks)
      afr[m][ks] = ldsfrag(Acur, wr * 128 + m * 16 + lr, ks * 4 + hi);
  if (MODE <= 1) stage_half(Ag + 128 * KK, (t + 1) * 64, ABUF(sh, b ^ 1) + 8192, tid);
  FENCE; BAR;
  __builtin_amdgcn_s_setprio(1);
#pragma unroll
  for (int m = 0; m < 4; ++m)
#pragma unroll
    for (int n = 0; n < 2; ++n)
#pragma unroll
      for (int ks = 0; ks < 2; ++ks)
        acc[m][n] = __builtin_amdgcn_mfma_f32_16x16x32_bf16(
            afr[m][ks], bfr[n][ks], acc[m][n], 0, 0, 0);
  __builtin_amdgcn_s_setprio(0);
  FENCE; BAR;

  // ---- P2: no reads; stage (t+2) B0 -> buf b (B fully consumed in P1)
  if (MODE == 0) stage_half(Wg, (t + 2) * 64, BBUF(sh, b), tid);
  FENCE; BAR;
  __builtin_amdgcn_s_setprio(1);
#pragma unroll
  for (int m = 0; m < 4; ++m)
#pragma unroll
    for (int n = 0; n < 2; ++n)
#pragma unroll
      for (int ks = 0; ks < 2; ++ks)
        acc[m][2 + n] = __builtin_amdgcn_mfma_f32_16x16x32_bf16(
            afr[m][ks], bfr[2 + n][ks], acc[m][2 + n], 0, 0, 0);
  __builtin_amdgcn_s_setprio(0);
  FENCE; BAR;

  // ---- P3: read A(mh1) (overwrites afr); stage (t+2) B1 -> buf b
#pragma unroll
  for (int m = 0; m < 4; ++m)
#pragma unroll
    for (int ks = 0; ks < 2; ++ks)
      afr[m][ks] = ldsfrag(Acur, wr * 128 + 64 + m * 16 + lr, ks * 4 + hi);
  if (MODE == 0) stage_half(Wg + 128 * KK, (t + 2) * 64, BBUF(sh, b) + 8192, tid);
  FENCE; BAR;
  __builtin_amdgcn_s_setprio(1);
#pragma unroll
  for (int m = 0; m < 4; ++m)
#pragma unroll
    for (int n = 0; n < 2; ++n)
#pragma unroll
      for (int ks = 0; ks < 2; ++ks)
        acc[4 + m][n] = __builtin_amdgcn_mfma_f32_16x16x32_bf16(
            afr[m][ks], bfr[n][ks], acc[4 + m][n], 0, 0, 0);
  __builtin_amdgcn_s_setprio(0);
  FENCE; BAR;

  // ---- P4: no reads; stage (t+2) A0 -> buf b (A fully consumed in P3);
  //          once-per-K-tile counted vmcnt
  if (MODE == 0) {
    stage_half(Ag, (t + 2) * 64, ABUF(sh, b), tid);
    WAITVM(6);                 // allow t+2 {B0,B1,A0} in flight; t+1 landed
  } else if (MODE == 1) {
    WAITVM(0);                 // drain: t63 fully landed
  }
  FENCE; BAR;
  __builtin_amdgcn_s_setprio(1);
#pragma unroll
  for (int m = 0; m < 4; ++m)
#pragma unroll
    for (int n = 0; n < 2; ++n)
#pragma unroll
      for (int ks = 0; ks < 2; ++ks)
        acc[4 + m][2 + n] = __builtin_amdgcn_mfma_f32_16x16x32_bf16(
            afr[m][ks], bfr[2 + n][ks], acc[4 + m][2 + n], 0, 0, 0);
  __builtin_amdgcn_s_setprio(0);
  FENCE; BAR;
}

__global__ __launch_bounds__(512, 2) void gemm_k(const u16* __restrict__ A,
                                                 const u16* __restrict__ W,
                                                 const float* __restrict__ scales,
                                                 const float* __restrict__ bias,
                                                 float* __restrict__ out) {
  __shared__ u16 sh[4 * 16384];  // 128 KiB: Ab0, Bb0, Ab1, Bb1 (256x64 each)

  // T1: XCD-aware swizzle (nwg = 256, divisible by 8)
  const int cpx = gridDim.x >> 3;
  const int wg = (blockIdx.x & 7) * cpx + (blockIdx.x >> 3);
  const int bm = wg >> 4;  // 16 x 16 tiles of 256x256
  const int bn = wg & 15;

  const int tid = threadIdx.x;
  const int lane = tid & 63;
  const int lr = lane & 15;
  const int hi = lane >> 4;
  const int wid = tid >> 6;
  const int wr = wid >> 2;  // 2 (M) x 4 (N) wave grid; wave tile 128x64
  const int wc = wid & 3;

  f32x4 acc[8][4] = {};

  const u16* Ag = A + (size_t)bm * 256 * KK;
  const u16* Wg = W + (size_t)bn * 256 * KK;

  // ---- prologue: tile0 all 4 halves + tile1 {B0,B1,A0}
  stage_half(Wg,             0, BBUF(sh, 0),        tid);
  stage_half(Wg + 128 * KK,  0, BBUF(sh, 0) + 8192, tid);
  stage_half(Ag,             0, ABUF(sh, 0),        tid);
  stage_half(Ag + 128 * KK,  0, ABUF(sh, 0) + 8192, tid);
  stage_half(Wg,            64, BBUF(sh, 1),        tid);
  stage_half(Wg + 128 * KK, 64, BBUF(sh, 1) + 8192, tid);
  stage_half(Ag,            64, ABUF(sh, 1),        tid);
  WAITVM(6);  // tile0 fully landed; tile1 {B0,B1,A0} may be in flight
  BAR;

  for (int t = 0; t < 62; ++t)
    do_tile<0>(t, acc, Ag, Wg, sh, tid, lr, hi, wr, wc);
  do_tile<1>(62, acc, Ag, Wg, sh, tid, lr, hi, wr, wc);
  do_tile<2>(63, acc, Ag, Wg, sh, tid, lr, hi, wr, wc);

  // ---- epilogue: dequant + bias, fp32 store
  // C/D layout (16x16x32): col = lane&15, row = (lane>>4)*4 + reg
  const int colb = bn * 256 + wc * 64 + lr;
  const int rowb0 = bm * 256 + wr * 128 + (hi << 2);
#pragma unroll
  for (int n = 0; n < 4; ++n) {
    const int col = colb + n * 16;
    const float sc = scales[col];
    const float bi = bias[col];
#pragma unroll
    for (int m = 0; m < 8; ++m) {
      const int row = rowb0 + m * 16;
#pragma unroll
      for (int j = 0; j < 4; ++j)
        out[(size_t)(row + j) * NN + col] = acc[m][n][j] * sc + bi;
    }
  }
}

// ---- fallback (ws too small): correct but slow -----------------------------
__global__ __launch_bounds__(256) void fb_k(const float* __restrict__ A,
                                            const int* __restrict__ W,
                                            const float* __restrict__ scales,
                                            const float* __restrict__ bias,
                                            float* __restrict__ out) {
  __shared__ float Arow[KK];
  const int m = blockIdx.y;
  const int n0 = blockIdx.x * 256;
  const int tid = threadIdx.x;
  for (int k = tid; k < KK; k += 256) Arow[k] = A[(size_t)m * KK + k];
  __syncthreads();
  const int n = n0 + tid;
  float acc = 0.f;
  const int* wrp = W + (size_t)n * KK;
  for (int k = 0; k < KK; ++k) acc += Arow[k] * (float)wrp[k];
  out[(size_t)m * NN + n] = acc * scales[n] + bias[n];
}

extern "C" void kernel_launch(void* const* d_in, const int* in_sizes, int n_in,
                              void* d_out, int out_size, void* d_ws, size_t ws_size,
                              hipStream_t stream) {
  const float* input = (const float*)d_in[0];
  const int* w8 = (const int*)d_in[1];
  const float* scales = (const float*)d_in[2];
  const float* bias = (const float*)d_in[3];
  float* out = (float*)d_out;

  const size_t nelem = (size_t)NN * KK;
  const size_t need = 2 * nelem * sizeof(u16);

  if (ws_size >= need) {
    u16* Wbf = (u16*)d_ws;
    u16* Abf = Wbf + nelem;
    cvt_w_k<<<8192, 256, 0, stream>>>(w8, Wbf);
    cvt_a_k<<<8192, 256, 0, stream>>>(input, Abf);
    gemm_k<<<256, 512, 0, stream>>>(Abf, Wbf, scales, bias, out);
  } else {
    dim3 grid(NN / 256, MM);
    fb_k<<<grid, 256, 0, stream>>>(input, w8, scales, bias, out);
  }
}